// Round 5
// baseline (390.671 us; speedup 1.0000x reference)
//
#include <hip/hip_runtime.h>

// CapsClass2d dynamic routing — K=16 MFMA, branch-free frag loads, 4.5 blk/CU.
// b=256, P=1152, C=10, os=is=16, 3 iterations.
// logits telescope: logits_k = dot(sum_{j<k} v_j, votes) -> only vsum state.
//
// votes[p] = W_p[160x16] @ X_p[16x256] via mfma_f32_16x16x16_bf16 (K=16=is0,
// all 64 lanes active, no zero-pad, no divergent loads — R4's 71us latency
// trap was 2 blk/CU + loads stuck inside `if(lane<32)` branches).
//   A[m=o][k]: m=lane&15, k=(lane>>4)*4+j     (4 bf16 = 1 VGPR pair)
//   B[k][n=b]: n=lane&15, k=(lane>>4)*4+j
//   C/D: col(b)=lane&15, row(o)=(lane>>4)*4+reg   (shape-determined, m89/m121+)
// Wave = 16 batches x 10 c x PW=4 positions; grid = 72 x 16 = 1152 blocks.
// vsum kept in LDS (stride 164 -> aligned b128, spread banks) to cut VGPRs.
// it=0: coup==0.1 exactly -> MFMA accumulator chains over p.

#define NPOS 1152
#define NC 10
#define IS 16
#define NB 256
#define CO 160
#define CAPS_EPS 1e-8f
#define PW 4
#define PCH (NPOS / (4 * PW))       // 72 p-chunks (16 positions each)
#define NA_SLOTS (NPOS * NC * 64)   // 737280 uint2 A-frag slots
#define NB_SLOTS (NPOS * 16 * 64)   // 1179648 uint2 B-frag slots
#define VS_STRIDE 164               // float stride: 16B-aligned, odd /16 group
#define SM_STRIDE 161

typedef __attribute__((ext_vector_type(4))) short bf16x4;
typedef __attribute__((ext_vector_type(8))) short bf16x8;
typedef __attribute__((ext_vector_type(4))) float floatx4;

#if defined(__has_builtin)
#  if __has_builtin(__builtin_amdgcn_mfma_f32_16x16x16bf16_1k)
#    define HAVE_MFMA16 1
#  endif
#endif

__device__ __forceinline__ unsigned f2bf(float x) {
    union { float f; unsigned u; } v; v.f = x;
    return (v.u + 0x7FFFu + ((v.u >> 16) & 1u)) >> 16;
}
__device__ __forceinline__ uint2 pack4(float4 a) {
    uint2 r;
    r.x = f2bf(a.x) | (f2bf(a.y) << 16);
    r.y = f2bf(a.z) | (f2bf(a.w) << 16);
    return r;
}

// Pre-convert W and poses into bf16 K=16 fragment-layout buffers (uint2/lane).
__global__ __launch_bounds__(256) void preconv_kernel(
    const float* __restrict__ poses, const float* __restrict__ weight,
    uint2* __restrict__ wsA, uint2* __restrict__ wsB)
{
    const int gid = blockIdx.x * 256 + threadIdx.x;
    if (gid < NA_SLOTS) {
        const int L = gid & 63, pc = gid >> 6;        // pc = p*10+c
        const int o = L & 15, q = L >> 4;
        const float4 w = *(const float4*)(weight + (size_t)pc * 256 + o * 16 + q * 4);
        wsA[gid] = pack4(w);
    } else {
        const int s = gid - NA_SLOTS;
        if (s < NB_SLOTS) {
            const int L = s & 63, pb = s >> 6;        // pb = p*16+bt
            const int bt = pb & 15, p = pb >> 4;
            const int bl = L & 15, q = L >> 4;
            const float4 x = *(const float4*)(poses +
                ((size_t)(bt * 16 + bl) * NPOS + p) * IS + q * 4);
            wsB[s] = pack4(x);
        }
    }
}

#ifdef HAVE_MFMA16
typedef bf16x4 FragT;
#define MFMA_OP(a, b, c) __builtin_amdgcn_mfma_f32_16x16x16bf16_1k(a, b, c, 0, 0, 0)

__device__ __forceinline__ FragT u2frag(uint2 u) {
    union { uint2 u; FragT f; } c; c.u = u; return c.f;
}
template <bool PC>
__device__ __forceinline__ FragT loadA(const uint2* wsA, const float* weight,
                                       int p, int c, int lane) {
    if (PC) return u2frag(wsA[((size_t)p * NC + c) * 64 + lane]);
    const int o = lane & 15, q = lane >> 4;
    const float4 w = *(const float4*)(weight + ((size_t)p * NC + c) * 256 + o * 16 + q * 4);
    return u2frag(pack4(w));
}
template <bool PC>
__device__ __forceinline__ FragT loadB(const uint2* wsB, const float* poses,
                                       int p, int bt, int lane) {
    if (PC) return u2frag(wsB[((size_t)p * 16 + bt) * 64 + lane]);
    const int bl = lane & 15, q = lane >> 4;
    const float4 x = *(const float4*)(poses +
        ((size_t)(bt * 16 + bl) * NPOS + p) * IS + q * 4);
    return u2frag(pack4(x));
}
#else
// Fallback: compose K=32 frags (upper quads zero) from the same uint2 buffers.
typedef bf16x8 FragT;
#define MFMA_OP(a, b, c) __builtin_amdgcn_mfma_f32_16x16x32_bf16(a, b, c, 0, 0, 0)

template <bool PC>
__device__ __forceinline__ FragT loadA(const uint2* wsA, const float* weight,
                                       int p, int c, int lane) {
    union { unsigned u[4]; FragT f; } r;
    const bool act = lane < 32;
    const int o = lane & 15, q = (lane >> 4) & 1;
    if (PC) {
        const uint2* base = wsA + ((size_t)p * NC + c) * 64 + q * 32 + o;
        const uint2 lo = base[0], hi = base[16];
        r.u[0] = act ? lo.x : 0u; r.u[1] = act ? lo.y : 0u;
        r.u[2] = act ? hi.x : 0u; r.u[3] = act ? hi.y : 0u;
    } else {
        const float4* s = (const float4*)(weight + ((size_t)p * NC + c) * 256 + o * 16 + q * 8);
        const uint2 lo = pack4(s[0]), hi = pack4(s[1]);
        r.u[0] = act ? lo.x : 0u; r.u[1] = act ? lo.y : 0u;
        r.u[2] = act ? hi.x : 0u; r.u[3] = act ? hi.y : 0u;
    }
    return r.f;
}
template <bool PC>
__device__ __forceinline__ FragT loadB(const uint2* wsB, const float* poses,
                                       int p, int bt, int lane) {
    union { unsigned u[4]; FragT f; } r;
    const bool act = lane < 32;
    const int bl = lane & 15, q = (lane >> 4) & 1;
    if (PC) {
        const uint2* base = wsB + ((size_t)p * 16 + bt) * 64 + q * 32 + bl;
        const uint2 lo = base[0], hi = base[16];
        r.u[0] = act ? lo.x : 0u; r.u[1] = act ? lo.y : 0u;
        r.u[2] = act ? hi.x : 0u; r.u[3] = act ? hi.y : 0u;
    } else {
        const float4* s = (const float4*)(poses +
            ((size_t)(bt * 16 + bl) * NPOS + p) * IS + q * 8);
        const uint2 lo = pack4(s[0]), hi = pack4(s[1]);
        r.u[0] = act ? lo.x : 0u; r.u[1] = act ? lo.y : 0u;
        r.u[2] = act ? hi.x : 0u; r.u[3] = act ? hi.y : 0u;
    }
    return r.f;
}
#endif

template <bool PC, int MODE>   // MODE: 0 = it0, 1 = it1, 2 = it2 (writes coup)
__global__ __launch_bounds__(256, 4) void caps_votes(
    const float* __restrict__ poses, const float* __restrict__ weight,
    const uint2* __restrict__ wsA, const uint2* __restrict__ wsB,
    const float* __restrict__ vsum, float* __restrict__ sbuf,
    float* __restrict__ out_coup)
{
    const int t    = threadIdx.x;
    const int wave = t >> 6, lane = t & 63;
    const int bcol = lane & 15, quad = lane >> 4;
    const int bt   = blockIdx.y, b0 = bt * 16;
    const int pbase = blockIdx.x * (4 * PW) + wave * PW;

    __shared__ float sh_vsum[16 * VS_STRIDE];
    __shared__ float s_merge[16 * SM_STRIDE];
    for (int k = t; k < 16 * SM_STRIDE; k += 256) s_merge[k] = 0.f;
    if (MODE > 0) {
        for (int k = t; k < 16 * CO; k += 256) {
            const int b = k / CO, j = k - b * CO;
            sh_vsum[b * VS_STRIDE + j] = vsum[(size_t)(b0 + b) * CO + j];
        }
    }
    __syncthreads();

    floatx4 sacc[NC];
#pragma unroll
    for (int c = 0; c < NC; ++c) sacc[c] = (floatx4)(0.f);

    for (int pi = 0; pi < PW; ++pi) {
        const int p = pbase + pi;
        const FragT bf = loadB<PC>(wsB, poses, p, bt, lane);

        if (MODE == 0) {
            // coup == 0.1 exactly -> accumulate votes straight into MFMA C
#pragma unroll
            for (int c = 0; c < NC; ++c)
                sacc[c] = MFMA_OP(loadA<PC>(wsA, weight, p, c, lane), bf, sacc[c]);
        } else {
            floatx4 acc[NC];
#pragma unroll
            for (int c = 0; c < NC; ++c)
                acc[c] = MFMA_OP(loadA<PC>(wsA, weight, p, c, lane), bf, (floatx4)(0.f));

            float lg[NC];
            float mx = -1e30f;
#pragma unroll
            for (int c = 0; c < NC; ++c) {
                const float4 vv = *(const float4*)&sh_vsum[bcol * VS_STRIDE + c * 16 + quad * 4];
                float pt = vv.x * acc[c][0] + vv.y * acc[c][1]
                         + vv.z * acc[c][2] + vv.w * acc[c][3];
                pt += __shfl_xor(pt, 16);
                pt += __shfl_xor(pt, 32);
                lg[c] = pt;
                mx = fmaxf(mx, pt);
            }
            float coup[NC], sum = 0.f;
#pragma unroll
            for (int c = 0; c < NC; ++c) { coup[c] = __expf(lg[c] - mx); sum += coup[c]; }
            const float inv = 1.f / sum;
#pragma unroll
            for (int c = 0; c < NC; ++c) coup[c] *= inv;

            if (MODE == 2 && quad == 0) {
                float* cp = out_coup + (size_t)(b0 + bcol) * (NC * NPOS) + p;
#pragma unroll
                for (int c = 0; c < NC; ++c) cp[c * NPOS] = coup[c];
            }

#pragma unroll
            for (int c = 0; c < NC; ++c)
#pragma unroll
                for (int r = 0; r < 4; ++r) sacc[c][r] += coup[c] * acc[c][r];
        }
    }

    // merge block's 4 waves in LDS, then one atomic pass to global
    const float scale = (MODE == 0) ? 0.1f : 1.f;
#pragma unroll
    for (int c = 0; c < NC; ++c)
#pragma unroll
        for (int r = 0; r < 4; ++r)
            atomicAdd(&s_merge[bcol * SM_STRIDE + c * 16 + quad * 4 + r], scale * sacc[c][r]);
    __syncthreads();
    for (int k = t; k < 16 * CO; k += 256) {
        const int b = k / CO, j = k - b * CO;
        unsafeAtomicAdd(&sbuf[(size_t)(b0 + b) * CO + j], s_merge[b * SM_STRIDE + j]);
    }
}

__global__ __launch_bounds__(256) void caps_squash_kernel(
    const float* __restrict__ rbias,   // [10, 16]
    float* __restrict__ sbuf,          // [256, 10, 16]
    float* __restrict__ vsum,          // [256, 10, 16]
    float* __restrict__ out_poses,     // [256, 10, 16]
    float* __restrict__ out_act,       // [256, 10]
    int it)
{
    const int b = blockIdx.x;
    const int t = threadIdx.x;
    if (t >= CO) return;
    const int c = t >> 4;

    const size_t idx = (size_t)b * CO + t;
    const float s = sbuf[idx] + rbias[t];
    float sq = s * s;
    sq += __shfl_xor(sq, 1);
    sq += __shfl_xor(sq, 2);
    sq += __shfl_xor(sq, 4);
    sq += __shfl_xor(sq, 8);
    const float f = (sq / (1.f + sq)) * rsqrtf(sq + CAPS_EPS);
    const float v = f * s;

    if (it < 2) {
        vsum[idx] += v;
        sbuf[idx] = 0.f;               // re-arm accumulator
    } else {
        out_poses[idx] = v;
        if ((t & 15) == 0) out_act[(size_t)b * NC + c] = sqrtf(f * f * sq + CAPS_EPS);
    }
}

extern "C" void kernel_launch(void* const* d_in, const int* in_sizes, int n_in,
                              void* d_out, int out_size, void* d_ws, size_t ws_size,
                              hipStream_t stream) {
    const float* poses  = (const float*)d_in[0];
    // d_in[1] (input_caps_activations) unused by the reference computation.
    const float* weight = (const float*)d_in[2];
    const float* rbias  = (const float*)d_in[3];

    float* out       = (float*)d_out;
    float* out_poses = out;                                   // 256*10*16
    float* out_act   = out + (size_t)NB * CO;                 // 256*10
    float* out_coup  = out_act + (size_t)NB * NC;             // 256*10*1152

    float* sbuf = (float*)d_ws;                               // 256*160 floats
    float* vsum = sbuf + (size_t)NB * CO;                     // 256*160 floats
    uint2* wsA  = (uint2*)((char*)d_ws + (size_t)2 * NB * CO * sizeof(float));
    uint2* wsB  = wsA + NA_SLOTS;

    const size_t need = (size_t)2 * NB * CO * sizeof(float)
                      + (size_t)(NA_SLOTS + NB_SLOTS) * sizeof(uint2);
    const bool pc = (ws_size >= need);

    hipMemsetAsync(d_ws, 0, (size_t)2 * NB * CO * sizeof(float), stream);

    const dim3 vgrid(PCH, 16), vblk(256);
    if (pc) {
        hipLaunchKernelGGL(preconv_kernel,
                           dim3((NA_SLOTS + NB_SLOTS) / 256), dim3(256), 0, stream,
                           poses, weight, wsA, wsB);
        hipLaunchKernelGGL((caps_votes<true, 0>), vgrid, vblk, 0, stream,
                           poses, weight, wsA, wsB, vsum, sbuf, out_coup);
        hipLaunchKernelGGL(caps_squash_kernel, dim3(NB), dim3(256), 0, stream,
                           rbias, sbuf, vsum, out_poses, out_act, 0);
        hipLaunchKernelGGL((caps_votes<true, 1>), vgrid, vblk, 0, stream,
                           poses, weight, wsA, wsB, vsum, sbuf, out_coup);
        hipLaunchKernelGGL(caps_squash_kernel, dim3(NB), dim3(256), 0, stream,
                           rbias, sbuf, vsum, out_poses, out_act, 1);
        hipLaunchKernelGGL((caps_votes<true, 2>), vgrid, vblk, 0, stream,
                           poses, weight, wsA, wsB, vsum, sbuf, out_coup);
        hipLaunchKernelGGL(caps_squash_kernel, dim3(NB), dim3(256), 0, stream,
                           rbias, sbuf, vsum, out_poses, out_act, 2);
    } else {
        hipLaunchKernelGGL((caps_votes<false, 0>), vgrid, vblk, 0, stream,
                           poses, weight, wsA, wsB, vsum, sbuf, out_coup);
        hipLaunchKernelGGL(caps_squash_kernel, dim3(NB), dim3(256), 0, stream,
                           rbias, sbuf, vsum, out_poses, out_act, 0);
        hipLaunchKernelGGL((caps_votes<false, 1>), vgrid, vblk, 0, stream,
                           poses, weight, wsA, wsB, vsum, sbuf, out_coup);
        hipLaunchKernelGGL(caps_squash_kernel, dim3(NB), dim3(256), 0, stream,
                           rbias, sbuf, vsum, out_poses, out_act, 1);
        hipLaunchKernelGGL((caps_votes<false, 2>), vgrid, vblk, 0, stream,
                           poses, weight, wsA, wsB, vsum, sbuf, out_coup);
        hipLaunchKernelGGL(caps_squash_kernel, dim3(NB), dim3(256), 0, stream,
                           rbias, sbuf, vsum, out_poses, out_act, 2);
    }
}